// Round 4
// baseline (793.183 us; speedup 1.0000x reference)
//
#include <hip/hip_runtime.h>
#include <math.h>

typedef __bf16 bf16x8 __attribute__((ext_vector_type(8)));
typedef float  f32x4  __attribute__((ext_vector_type(4)));

#define NROWS 6272
#define CDIM  768
#define HIDD  3072

#define EPI_BIAS 0
#define EPI_GELU 2
#define EPI_RES  3

__device__ __forceinline__ void gload16(const void* g, void* l) {
    __builtin_amdgcn_global_load_lds(
        (const __attribute__((address_space(1))) void*)(uintptr_t)g,
        (__attribute__((address_space(3))) void*)(uintptr_t)l,
        16, 0, 0);
}

// m204 bijective XCD-chunked swizzle
__device__ __forceinline__ void xcd_swz(int& m, int& n) {
    const int gx = gridDim.x;
    const int nwg = gx * gridDim.y;
    const int orig = blockIdx.x + gx * blockIdx.y;
    const int q = nwg >> 3, r = nwg & 7;
    const int xcd = orig & 7, loc = orig >> 3;
    const int wg = (xcd < r ? xcd * (q + 1) : r * (q + 1) + (xcd - r) * q) + loc;
    m = wg / gx;
    n = wg % gx;
}

// ---------------- weight transpose + cast: W (K x N fp32) -> WT (N x K bf16) ----------------
__global__ __launch_bounds__(256) void transpose_w(const float* __restrict__ W,
                                                   __bf16* __restrict__ WT,
                                                   int K, int N) {
    __shared__ float tile[32][33];
    const int tx = threadIdx.x, ty = threadIdx.y;
    const int kb = blockIdx.y * 32, nb = blockIdx.x * 32;
    #pragma unroll
    for (int r = 0; r < 4; ++r)
        tile[ty + r * 8][tx] = W[(size_t)(kb + ty + r * 8) * N + nb + tx];
    __syncthreads();
    #pragma unroll
    for (int r = 0; r < 4; ++r)
        WT[(size_t)(nb + ty + r * 8) * K + kb + tx] = (__bf16)tile[tx][ty + r * 8];
}

// ---------------- LayerNorm (fp32 in, bf16 out) ----------------
__global__ __launch_bounds__(256) void ln_kernel(const float* __restrict__ x,
                                                 const float* __restrict__ sc,
                                                 const float* __restrict__ bi,
                                                 __bf16* __restrict__ o) {
    const int row = blockIdx.x;
    const float* xr = x + (size_t)row * CDIM;
    __bf16* orow = o + (size_t)row * CDIM;
    const int t = threadIdx.x;

    float v0 = xr[t], v1 = xr[t + 256], v2 = xr[t + 512];
    float s = v0 + v1 + v2;

    __shared__ float sm[8];
    #pragma unroll
    for (int off = 32; off > 0; off >>= 1) s += __shfl_xor(s, off);
    const int wid = t >> 6, lane = t & 63;
    if (lane == 0) sm[wid] = s;
    __syncthreads();
    const float mu = (sm[0] + sm[1] + sm[2] + sm[3]) * (1.0f / 768.0f);

    const float d0 = v0 - mu, d1 = v1 - mu, d2 = v2 - mu;
    float s2 = d0 * d0 + d1 * d1 + d2 * d2;
    #pragma unroll
    for (int off = 32; off > 0; off >>= 1) s2 += __shfl_xor(s2, off);
    if (lane == 0) sm[4 + wid] = s2;
    __syncthreads();
    const float var = (sm[4] + sm[5] + sm[6] + sm[7]) * (1.0f / 768.0f);
    const float r = rsqrtf(var + 1e-6f);

    orow[t]       = (__bf16)(d0 * r * sc[t]       + bi[t]);
    orow[t + 256] = (__bf16)(d1 * r * sc[t + 256] + bi[t + 256]);
    orow[t + 512] = (__bf16)(d2 * r * sc[t + 512] + bi[t + 512]);
}

// ---------------- generic MFMA GEMM, tile BM x BN, BK=32, 4 waves ----------------
// A: M x K bf16 (stride lda). BT: N x K bf16 (dense). Verified m97 fragment maps.
template <int EPI, int BM, int BN>
__global__ __launch_bounds__(256) void mm_bf16(const __bf16* __restrict__ A, int lda,
                                               const __bf16* __restrict__ BT,
                                               const float* __restrict__ bias,
                                               const float* __restrict__ gamma,
                                               const float* __restrict__ res, int ldr,
                                               void* __restrict__ outv, int ldo,
                                               int K) {
    constexpr int RF = BM / 32;   // row frags per wave
    constexpr int CF = BN / 32;   // col frags per wave
    __shared__ __bf16 As[BM * 32];
    __shared__ __bf16 Bs[BN * 32];
    int mb, nb;
    xcd_swz(mb, nb);
    const int m0 = mb * BM, n0 = nb * BN;

    const int t  = threadIdx.x;
    const int w  = t >> 6;
    const int l  = t & 63;
    const int wm = w >> 1, wn = w & 1;
    const int rsub = t >> 2;
    const int ke   = (t & 3) * 8;
    const int fr = l & 15;
    const int kq = (l >> 4) * 8;

    f32x4 acc[RF][CF];
    #pragma unroll
    for (int i = 0; i < RF; ++i)
        #pragma unroll
        for (int j = 0; j < CF; ++j)
            acc[i][j] = f32x4{0.f, 0.f, 0.f, 0.f};

    const __bf16* gA = A  + (size_t)(m0 + rsub) * lda + ke;
    const __bf16* gB = BT + (size_t)(n0 + rsub) * K   + ke;
    __bf16* lA = &As[w * 512];
    __bf16* lB = &Bs[w * 512];

    for (int k0 = 0; k0 < K; k0 += 32) {
        __syncthreads();
        #pragma unroll
        for (int h = 0; h < BM / 64; ++h)
            gload16(gA + (size_t)(h * 64) * lda + k0, lA + h * 2048);
        #pragma unroll
        for (int h = 0; h < BN / 64; ++h)
            gload16(gB + (size_t)(h * 64) * K + k0, lB + h * 2048);
        __syncthreads();

        bf16x8 av[RF], bv[CF];
        #pragma unroll
        for (int i = 0; i < RF; ++i)
            av[i] = *(const bf16x8*)&As[(wm * (BM / 2) + i * 16 + fr) * 32 + kq];
        #pragma unroll
        for (int j = 0; j < CF; ++j)
            bv[j] = *(const bf16x8*)&Bs[(wn * (BN / 2) + j * 16 + fr) * 32 + kq];
        #pragma unroll
        for (int i = 0; i < RF; ++i)
            #pragma unroll
            for (int j = 0; j < CF; ++j)
                acc[i][j] = __builtin_amdgcn_mfma_f32_16x16x32_bf16(av[i], bv[j], acc[i][j], 0, 0, 0);
    }

    const int row0 = m0 + wm * (BM / 2);
    const int col0 = n0 + wn * (BN / 2);
    #pragma unroll
    for (int i = 0; i < RF; ++i) {
        #pragma unroll
        for (int j = 0; j < CF; ++j) {
            const int col = col0 + j * 16 + fr;
            const float bsv = bias[col];
            #pragma unroll
            for (int r = 0; r < 4; ++r) {
                const int row = row0 + i * 16 + (l >> 4) * 4 + r;
                float z = acc[i][j][r] + bsv;
                if (EPI == EPI_BIAS) {
                    ((__bf16*)outv)[(size_t)row * ldo + col] = (__bf16)z;
                } else if (EPI == EPI_GELU) {
                    const float z3 = z * z * z;
                    z = 0.5f * z * (1.0f + tanhf(0.7978845608028654f * (z + 0.044715f * z3)));
                    ((__bf16*)outv)[(size_t)row * ldo + col] = (__bf16)z;
                } else {  // EPI_RES
                    const float zz = res[(size_t)row * ldr + col] + z * gamma[col];
                    ((float*)outv)[(size_t)row * ldo + col] = zz;
                }
            }
        }
    }
}

// ---------------- persistent gated-CSSM recurrence ----------------
// 196 blocks x 32 rows, 512 threads (8 waves). hx/hy resident in LDS
// (XOR-swizzled: elem ^ ((row&7)<<3) so stride-1536B frag reads are 2-way = free).
// u held in registers in C/D fragment layout. W_gate streamed from L2 per step.
// Steps ts=1..7 (t=0 collapsed to hx=u, hy=0 since initial state is zero).
#define GROWS 32
__global__ __launch_bounds__(512) void gate_persist(const __bf16* __restrict__ u,
                                                    const __bf16* __restrict__ WTg,
                                                    const float* __restrict__ b_gate,
                                                    const float* __restrict__ ad,
                                                    const float* __restrict__ br,
                                                    __bf16* __restrict__ hx_out) {
    __shared__ __bf16 hxs[GROWS * 768];
    __shared__ __bf16 hys[GROWS * 768];

    const int t = threadIdx.x;
    const int w = t >> 6;          // 0..7
    const int l = t & 63;
    const int row_base = blockIdx.x * GROWS;

    // stage u -> hxs (hx0 = u), zero hys
    #pragma unroll
    for (int p = 0; p < 6; ++p) {
        const int idx = p * 512 + t;              // 0..3071
        const int row = idx / 96, c8 = idx % 96;
        const uint4 v = *(const uint4*)&u[(size_t)(row_base + row) * 768 + c8 * 8];
        const int le = (row * 768 + c8 * 8) ^ ((row & 7) << 3);
        *(uint4*)&hxs[le] = v;
        *(uint4*)&hys[le] = make_uint4(0u, 0u, 0u, 0u);
    }
    __syncthreads();

    const int fr = l & 15;
    const int q4 = l >> 4;         // 0..3
    const int c0 = w * 96;         // 96 cols per wave

    // per-colfrag constants
    float bias_c[6], a_c[6], b_c[6];
    #pragma unroll
    for (int cf = 0; cf < 6; ++cf) {
        const int col = c0 + cf * 16 + fr;
        bias_c[cf] = b_gate[col];
        a_c[cf]    = ad[col];
        b_c[cf]    = br[col];
    }
    // u in registers, C/D fragment layout (col=fr, row=q4*4+r, rf half adds 16)
    float ur[2][6][4];
    #pragma unroll
    for (int rf = 0; rf < 2; ++rf)
        #pragma unroll
        for (int cf = 0; cf < 6; ++cf)
            #pragma unroll
            for (int r = 0; r < 4; ++r) {
                const int row = rf * 16 + q4 * 4 + r;
                const int col = c0 + cf * 16 + fr;
                ur[rf][cf][r] = (float)hxs[(row * 768 + col) ^ ((row & 7) << 3)];
            }

    for (int ts = 1; ts < 8; ++ts) {
        f32x4 acc[2][6];
        #pragma unroll
        for (int rf = 0; rf < 2; ++rf)
            #pragma unroll
            for (int cf = 0; cf < 6; ++cf)
                acc[rf][cf] = f32x4{0.f, 0.f, 0.f, 0.f};

        // K in [0,768): A from hxs.  No barrier inside -> loads pipeline freely.
        for (int k0 = 0; k0 < 768; k0 += 32) {
            bf16x8 bv[6];
            #pragma unroll
            for (int cf = 0; cf < 6; ++cf)
                bv[cf] = *(const bf16x8*)&WTg[(size_t)(c0 + cf * 16 + fr) * 1536 + k0 + q4 * 8];
            bf16x8 av[2];
            #pragma unroll
            for (int rf = 0; rf < 2; ++rf) {
                const int row = rf * 16 + fr;
                av[rf] = *(const bf16x8*)&hxs[(row * 768 + k0 + q4 * 8) ^ ((row & 7) << 3)];
            }
            __builtin_amdgcn_s_setprio(1);
            #pragma unroll
            for (int rf = 0; rf < 2; ++rf)
                #pragma unroll
                for (int cf = 0; cf < 6; ++cf)
                    acc[rf][cf] = __builtin_amdgcn_mfma_f32_16x16x32_bf16(av[rf], bv[cf], acc[rf][cf], 0, 0, 0);
            __builtin_amdgcn_s_setprio(0);
        }
        // K in [768,1536): A from hys
        for (int k0 = 0; k0 < 768; k0 += 32) {
            bf16x8 bv[6];
            #pragma unroll
            for (int cf = 0; cf < 6; ++cf)
                bv[cf] = *(const bf16x8*)&WTg[(size_t)(c0 + cf * 16 + fr) * 1536 + 768 + k0 + q4 * 8];
            bf16x8 av[2];
            #pragma unroll
            for (int rf = 0; rf < 2; ++rf) {
                const int row = rf * 16 + fr;
                av[rf] = *(const bf16x8*)&hys[(row * 768 + k0 + q4 * 8) ^ ((row & 7) << 3)];
            }
            __builtin_amdgcn_s_setprio(1);
            #pragma unroll
            for (int rf = 0; rf < 2; ++rf)
                #pragma unroll
                for (int cf = 0; cf < 6; ++cf)
                    acc[rf][cf] = __builtin_amdgcn_mfma_f32_16x16x32_bf16(av[rf], bv[cf], acc[rf][cf], 0, 0, 0);
            __builtin_amdgcn_s_setprio(0);
        }
        __syncthreads();   // all waves done reading old state

        const bool last = (ts == 7);
        #pragma unroll
        for (int rf = 0; rf < 2; ++rf)
            #pragma unroll
            for (int cf = 0; cf < 6; ++cf)
                #pragma unroll
                for (int r = 0; r < 4; ++r) {
                    const int row = rf * 16 + q4 * 4 + r;
                    const int col = c0 + cf * 16 + fr;
                    const int le = (row * 768 + col) ^ ((row & 7) << 3);
                    const float z = acc[rf][cf][r] + bias_c[cf];
                    const float g = 1.0f / (1.0f + __expf(-z));
                    const float hx = (float)hxs[le];
                    const float hy = (float)hys[le];
                    const float nx = g * (a_c[cf] * hx - b_c[cf] * hy) + ur[rf][cf][r];
                    if (last) {
                        hx_out[(size_t)(row_base + row) * 768 + col] = (__bf16)nx;
                    } else {
                        hxs[le] = (__bf16)nx;
                        hys[le] = (__bf16)(g * (b_c[cf] * hx + a_c[cf] * hy));
                    }
                }
        __syncthreads();   // updates visible before next step's GEMM
    }
}

extern "C" void kernel_launch(void* const* d_in, const int* in_sizes, int n_in,
                              void* d_out, int out_size, void* d_ws, size_t ws_size,
                              hipStream_t stream) {
    (void)in_sizes; (void)n_in; (void)out_size;
    const float* x      = (const float*)d_in[0];
    const float* ln1_s  = (const float*)d_in[1];
    const float* ln1_b  = (const float*)d_in[2];
    const float* W_in   = (const float*)d_in[3];
    const float* b_in   = (const float*)d_in[4];
    const float* W_gate = (const float*)d_in[5];
    const float* b_gate = (const float*)d_in[6];
    const float* a_dec  = (const float*)d_in[7];
    const float* b_rot  = (const float*)d_in[8];
    const float* W_out  = (const float*)d_in[9];
    const float* b_out  = (const float*)d_in[10];
    const float* gamma1 = (const float*)d_in[11];
    const float* ln2_s  = (const float*)d_in[12];
    const float* ln2_b  = (const float*)d_in[13];
    const float* W1     = (const float*)d_in[14];
    const float* b1     = (const float*)d_in[15];
    const float* W2     = (const float*)d_in[16];
    const float* b2     = (const float*)d_in[17];
    const float* gamma2 = (const float*)d_in[18];
    float* out = (float*)d_out;

    // ---- workspace layout (bytes), total 100,859,904 ----
    if (ws_size < 100859904) return;
    char* w8 = (char*)d_ws;
    __bf16* WT_in   = (__bf16*)(w8);                 // 768x768  bf16
    __bf16* WT_gate = (__bf16*)(w8 + 1179648);       // 768x1536 bf16
    __bf16* WT_out  = (__bf16*)(w8 + 3538944);       // 768x768  bf16
    __bf16* WT1     = (__bf16*)(w8 + 4718592);       // 3072x768 bf16
    __bf16* WT2     = (__bf16*)(w8 + 9437184);       // 768x3072 bf16
    float*  x1      = (float*)(w8 + 14155776);       // NC fp32
    __bf16* xn      = (__bf16*)(w8 + 33423360);      // NC bf16 (both LN outputs)
    __bf16* u       = (__bf16*)(w8 + 43057152);      // NC bf16
    __bf16* hx_out  = (__bf16*)(w8 + 52690944);      // NC bf16
    __bf16* h       = (__bf16*)(w8 + 62324736);      // NROWS x 3072 bf16

    const dim3 tb(32, 8);
    transpose_w<<<dim3(24, 24), tb, 0, stream>>>(W_in,   WT_in,   768,  768);
    transpose_w<<<dim3(24, 48), tb, 0, stream>>>(W_gate, WT_gate, 1536, 768);
    transpose_w<<<dim3(24, 24), tb, 0, stream>>>(W_out,  WT_out,  768,  768);
    transpose_w<<<dim3(96, 24), tb, 0, stream>>>(W1,     WT1,     768,  3072);
    transpose_w<<<dim3(24, 96), tb, 0, stream>>>(W2,     WT2,     3072, 768);

    const dim3 gC(12, 49);   // N=768 GEMMs: 128x64 tiles, 588 blocks
    const dim3 gH(24, 49);   // GELU: 128x128, 1176 blocks

    // branch 1
    ln_kernel<<<NROWS, 256, 0, stream>>>(x, ln1_s, ln1_b, xn);
    mm_bf16<EPI_BIAS, 128, 64><<<gC, 256, 0, stream>>>(xn, 768, WT_in, b_in,
                                                       nullptr, nullptr, 0, u, 768, 768);
    gate_persist<<<196, 512, 0, stream>>>(u, WT_gate, b_gate, a_dec, b_rot, hx_out);
    mm_bf16<EPI_RES, 128, 64><<<gC, 256, 0, stream>>>(hx_out, 768, WT_out, b_out,
                                                      gamma1, x, 768, x1, 768, 768);
    // branch 2
    ln_kernel<<<NROWS, 256, 0, stream>>>(x1, ln2_s, ln2_b, xn);
    mm_bf16<EPI_GELU, 128, 128><<<gH, 256, 0, stream>>>(xn, 768, WT1, b1,
                                                        nullptr, nullptr, 0, h, 3072, 768);
    mm_bf16<EPI_RES, 128, 64><<<gC, 256, 0, stream>>>(h, 3072, WT2, b2,
                                                      gamma2, x1, 768, out, 768, 3072);
}